// Round 10
// baseline (84.118 us; speedup 1.0000x reference)
//
#include <hip/hip_runtime.h>
#include <math.h>

typedef __attribute__((ext_vector_type(8))) unsigned short ushort8;
typedef __attribute__((ext_vector_type(8))) __bf16 bf16x8;
typedef __attribute__((ext_vector_type(4))) float f32x4;

constexpr int   CDIM  = 256;     // channels
constexpr int   HWSP  = 4096;    // H*W
constexpr int   PPB   = 32;      // positions per tile
constexpr float SQRTC = 0.031622776601683794f;  // sqrt(0.001)
constexpr float EPSR  = 1e-6f;

__device__ inline unsigned short f2bf(float x) {  // RNE f32 -> bf16
    unsigned int u = __float_as_uint(x);
    u += 0x7FFFu + ((u >> 16) & 1u);
    return (unsigned short)(u >> 16);
}

// async global->LDS, 16B/lane: dest = wave-uniform base + lane*16 (linear),
// source = per-lane global address. No data VGPRs on the staging path.
__device__ inline void glds16(const float* g, void* l) {
    __builtin_amdgcn_global_load_lds(
        (const __attribute__((address_space(1))) void*)g,
        (__attribute__((address_space(3))) void*)l, 16, 0, 0);
}

// ---- builder: w[256] (circular-conv kernel) -> Wpk in per-lane MFMA B-frag order
// Wpk[ks(8)][tile(16)][lane(64)][j(8)], value = w[(outch-ch)&255],
// outch = tile*16 + (lane&15), ch = ks*32 + (lane>>4)*8 + j.
__global__ void build_wpk(const float* __restrict__ phi,
                          unsigned short* __restrict__ wpk) {
    __shared__ float w[256];
    const int d = threadIdx.x;
    {
        const float step = 6.283185307179586f / 256.0f;
        double s = 0.0;
        for (int k = 1; k <= 127; ++k) {
            int kd = (k * d) & 255;             // exact mod-2pi reduction
            s += 2.0 * (double)cosf(10.0f * phi[k] + step * (float)kd);
        }
        s += (double)cosf(10.0f * phi[0]);
        double c128 = (double)cosf(10.0f * phi[128]);
        s += (d & 1) ? -c128 : c128;
        w[d] = (float)(s * (1.0 / 256.0));      // irfft drops imag at DC/Nyq
    }
    __syncthreads();
    const int l = d & 63, q = d >> 6;
    for (int blk = q; blk < 128; blk += 4) {    // blk = ks*16 + tile
        const int outc = (blk & 15) * 16 + (l & 15);
        const int ch0  = (blk >> 4) * 32 + (l >> 4) * 8;
        ushort8 u;
        #pragma unroll
        for (int j = 0; j < 8; ++j)
            u[j] = f2bf(w[(outc - (ch0 + j)) & 255]);
        *reinterpret_cast<ushort8*>(&wpk[(size_t)(blk * 64 + l) * 8]) = u;
    }
}

// radial Fourier gate: a0 + sum_{n=1..16} a[n-1]cos(rn) + b[n-1]sin(rn)
__device__ inline float fourier_gate(float r, float A0,
                                     const float* __restrict__ a,
                                     const float* __restrict__ b) {
    float sn, cs;
    sincosf(r, &sn, &cs);
    float c = cs, s = sn, f = A0;
    #pragma unroll
    for (int n = 0; n < 16; ++n) {
        f = fmaf(a[n], c, f);
        f = fmaf(b[n], s, f);
        float c2 = fmaf(c, cs, -s * sn);
        float s2 = fmaf(s, cs,  c * sn);
        c = c2; s = s2;
    }
    return f;
}

__global__ __launch_bounds__(256, 4)
void fused_mfma(const float* __restrict__ x,
                const float* __restrict__ a0_1, const float* __restrict__ a1,
                const float* __restrict__ b1,
                const float* __restrict__ a0_2, const float* __restrict__ a2,
                const float* __restrict__ b2,
                const float* __restrict__ phi,
                const float* __restrict__ alpha, const float* __restrict__ beta,
                const unsigned short* __restrict__ wpk,
                float* __restrict__ out) {
    __shared__ __align__(16) float Xf32[CDIM][PPB];   // 32 KB, native [ch][pos]
    __shared__ __align__(16) float stats[3][4][PPB];  // nsq / S0 / S_alt
    __shared__ __align__(16) float sobuf[PPB];

    const int t  = threadIdx.x;
    const int l  = t & 63;
    const int g  = t >> 6;                      // wave id
    const int lr = l & 15;
    const int lk = l >> 4;
    const int b  = blockIdx.x >> 7;             // 128 tiles per batch image
    const int s0 = (blockIdx.x & 127) * PPB;
    const float* xb = x + (size_t)b * CDIM * HWSP + s0;

    // ---- stage: async global->LDS, f32, native layout. 8 instrs/wave,
    //      whole 32KB tile in flight at once (zero data-VGPR pressure). ----
    #pragma unroll
    for (int i = 0; i < 8; ++i) {
        const int ch0 = g * 64 + i * 8;         // wave-uniform LDS base row
        const float* gp = xb + (size_t)(ch0 + (l >> 3)) * HWSP + (l & 7) * 4;
        glds16(gp, &Xf32[ch0][0]);
    }
    __syncthreads();                            // vmcnt drain + barrier

    // ---- stats from LDS (f32, pre-rounding): nsq / S0 / S_alt per position ----
    {
        const int co   = t >> 3;                // channel octet 0..31
        const int posq = t & 7;                 // position quad 0..7
        f32x4 vns = {0,0,0,0}, vs0 = {0,0,0,0}, vsa = {0,0,0,0};
        #pragma unroll
        for (int j = 0; j < 8; ++j) {
            f32x4 v = *reinterpret_cast<const f32x4*>(&Xf32[co * 8 + j][posq * 4]);
            vns += v * v;
            vs0 += v;
            vsa  = (j & 1) ? vsa - v : vsa + v; // (-1)^ch, ch = co*8+j
        }
        #pragma unroll
        for (int r = 0; r < 4; ++r) {           // reduce lanes sharing posq
            float aa = vns[r], ss = vs0[r], mm = vsa[r];
            aa += __shfl_xor(aa, 8, 64); aa += __shfl_xor(aa, 16, 64); aa += __shfl_xor(aa, 32, 64);
            ss += __shfl_xor(ss, 8, 64); ss += __shfl_xor(ss, 16, 64); ss += __shfl_xor(ss, 32, 64);
            mm += __shfl_xor(mm, 8, 64); mm += __shfl_xor(mm, 16, 64); mm += __shfl_xor(mm, 32, 64);
            vns[r] = aa; vs0[r] = ss; vsa[r] = mm;
        }
        if (l < 8) {                            // one writer per posq per wave
            *reinterpret_cast<f32x4*>(&stats[0][g][l * 4]) = vns;
            *reinterpret_cast<f32x4*>(&stats[1][g][l * 4]) = vs0;
            *reinterpret_cast<f32x4*>(&stats[2][g][l * 4]) = vsa;
        }
    }
    __syncthreads();                            // stats ready

    // ---- scalar pass (t<32), hidden under other waves' MFMA ----
    // Parseval: ||dot||^2 = nsq - [S0^2 sin^2(10 phi0) + Sa^2 sin^2(10 phi128)]/256
    if (t < PPB) {
        float nsq = stats[0][0][t] + stats[0][1][t] + stats[0][2][t] + stats[0][3][t];
        float S0  = stats[1][0][t] + stats[1][1][t] + stats[1][2][t] + stats[1][3][t];
        float Sa  = stats[2][0][t] + stats[2][1][t] + stats[2][2][t] + stats[2][3][t];
        float sin0 = sinf(10.0f * phi[0]);
        float sinN = sinf(10.0f * phi[128]);
        float n0  = sqrtf(nsq);
        float rn0 = fmaxf(n0, EPSR);
        float arg = fminf(SQRTC * rn0, 1.0f - 1e-5f);
        float ls  = atanhf(arg) / (SQRTC * rn0);
        float r1  = fmaxf(ls * n0, EPSR);
        float s1  = ls * fourier_gate(r1, a0_1[0], a1, b1);
        float dn2 = fmaxf(nsq - (S0 * S0 * sin0 * sin0 + Sa * Sa * sinN * sinN)
                                 * (1.0f / 256.0f), 0.f);
        float nv  = sqrtf(dn2) * fabsf(s1);     // ||v0||
        float r2  = fmaxf(nv, EPSR);
        float f2  = fourier_gate(r2, a0_2[0], a2, b2);
        float rn1 = fmaxf(fabsf(f2) * nv, EPSR);
        float es  = tanhf(SQRTC * rn1) / (SQRTC * rn1);
        sobuf[t]  = alpha[0] * es * f2 * s1;    // out = so*dot + beta*h0
    }

    // ---- MFMA: D[pos][outch] = X . Wt ; A-frags via LDS transpose-read+cvt ----
    f32x4 acc[2][4];
    #pragma unroll
    for (int m = 0; m < 2; ++m)
        #pragma unroll
        for (int n = 0; n < 4; ++n)
            acc[m][n] = f32x4{0.f, 0.f, 0.f, 0.f};

    #pragma unroll
    for (int ks = 0; ks < 8; ++ks) {
        const int ch0 = ks * 32 + lk * 8;       // this lane's k-slice
        bf16x8 af[2], bw[4];
        #pragma unroll
        for (int m = 0; m < 2; ++m) {           // transpose-read: 8 x b32
            const int pos = m * 16 + lr;        // broadcast across lk groups
            bf16x8 u;
            #pragma unroll
            for (int j = 0; j < 8; ++j)
                u[j] = (__bf16)Xf32[ch0 + j][pos];  // v_cvt (RNE) per elem
            af[m] = u;
        }
        #pragma unroll
        for (int n = 0; n < 4; ++n)             // B: W frags, coalesced L2-hot
            bw[n] = __builtin_bit_cast(bf16x8,
                *reinterpret_cast<const ushort8*>(
                    &wpk[(size_t)((ks * 16 + g * 4 + n) * 64 + l) * 8]));
        #pragma unroll
        for (int m = 0; m < 2; ++m)
            #pragma unroll
            for (int n = 0; n < 4; ++n)
                acc[m][n] = __builtin_amdgcn_mfma_f32_16x16x32_bf16(
                    af[m], bw[n], acc[m][n], 0, 0, 0);
    }
    __syncthreads();                            // sobuf ready

    // ---- epilogue: reg r = 4 consecutive positions -> dwordx4 stores ----
    const float bb = beta[0];
    float* ob = out + (size_t)b * CDIM * HWSP + s0;
    if (bb == 0.f) {                            // uniform branch
        #pragma unroll
        for (int m = 0; m < 2; ++m) {
            const int p0 = m * 16 + lk * 4;
            const f32x4 sob = *reinterpret_cast<const f32x4*>(&sobuf[p0]);
            #pragma unroll
            for (int n = 0; n < 4; ++n) {
                const int outc = (g * 4 + n) * 16 + lr;
                f32x4 vv = acc[m][n] * sob;
                *reinterpret_cast<f32x4*>(&ob[(size_t)outc * HWSP + p0]) = vv;
            }
        }
    } else {                                    // residual path (x re-read, L2-hot)
        #pragma unroll
        for (int m = 0; m < 2; ++m) {
            const int p0 = m * 16 + lk * 4;
            const f32x4 sob = *reinterpret_cast<const f32x4*>(&sobuf[p0]);
            #pragma unroll
            for (int n = 0; n < 4; ++n) {
                const int outc = (g * 4 + n) * 16 + lr;
                const f32x4 xv = *reinterpret_cast<const f32x4*>(
                                     &xb[(size_t)outc * HWSP + p0]);
                f32x4 vv = acc[m][n] * sob + bb * xv;
                *reinterpret_cast<f32x4*>(&ob[(size_t)outc * HWSP + p0]) = vv;
            }
        }
    }
}

extern "C" void kernel_launch(void* const* d_in, const int* in_sizes, int n_in,
                              void* d_out, int out_size, void* d_ws, size_t ws_size,
                              hipStream_t stream) {
    const float* x     = (const float*)d_in[0];
    const float* a0_1  = (const float*)d_in[1];
    const float* a1    = (const float*)d_in[2];
    const float* b1    = (const float*)d_in[3];
    const float* a0_2  = (const float*)d_in[4];
    const float* a2    = (const float*)d_in[5];
    const float* b2    = (const float*)d_in[6];
    const float* phi   = (const float*)d_in[7];
    const float* alpha = (const float*)d_in[8];
    const float* beta  = (const float*)d_in[9];

    unsigned short* wpk = (unsigned short*)d_ws;            // 128 KB

    build_wpk<<<1, 256, 0, stream>>>(phi, wpk);

    const int B = in_sizes[0] / (CDIM * HWSP);              // 32
    fused_mfma<<<dim3(B * (HWSP / PPB)), dim3(256), 0, stream>>>(
        x, a0_1, a1, b1, a0_2, a2, b2, phi, alpha, beta, wpk, (float*)d_out);
}